// Round 1
// 701.312 us; speedup vs baseline: 1.3223x; 1.3223x over previous
//
#include <hip/hip_runtime.h>
#include <hip/hip_bf16.h>

#define T_TOK 1024
#define H_DIM 2048
#define NH 16
#define NKV 4
#define HD 128
#define NEXP 8
#define I_DIM 768
#define EPSF 1e-6f

typedef unsigned short ushort_t;
typedef __attribute__((ext_vector_type(8))) _Float16 half8;
typedef __attribute__((ext_vector_type(4))) float f32x4;
typedef __attribute__((ext_vector_type(4))) unsigned short us4;

__device__ __forceinline__ ushort_t f2h(float x) {
    _Float16 h = (_Float16)x;
    return __builtin_bit_cast(ushort_t, h);
}
__device__ __forceinline__ float h2f_(ushort_t u) {
    return (float)__builtin_bit_cast(_Float16, u);
}
__device__ __forceinline__ void gld16(const ushort_t* g, ushort_t* l) {
    __builtin_amdgcn_global_load_lds(
        (const __attribute__((address_space(1))) unsigned int*)g,
        (__attribute__((address_space(3))) unsigned int*)l, 16, 0, 0);
}

// ---------------- residual add + RMSNorm -> res f32, h as f16 hi/lo planes ----------------
__global__ __launch_bounds__(256) void add_rms1(const float* __restrict__ a,
                                                const float* __restrict__ b,
                                                const float* __restrict__ w,
                                                float* __restrict__ res,
                                                ushort_t* __restrict__ hh,
                                                ushort_t* __restrict__ hl) {
    int t = blockIdx.x, tid = threadIdx.x;
    float v[8];
    float ss = 0.f;
#pragma unroll
    for (int i = 0; i < 8; i++) {
        int idx = t * H_DIM + tid + i * 256;
        v[i] = a[idx] + b[idx];
        res[idx] = v[i];
        ss += v[i] * v[i];
    }
#pragma unroll
    for (int o = 32; o; o >>= 1) ss += __shfl_down(ss, o);
    __shared__ float red[4];
    if ((tid & 63) == 0) red[tid >> 6] = ss;
    __syncthreads();
    float tot = red[0] + red[1] + red[2] + red[3];
    float scale = rsqrtf(tot / (float)H_DIM + EPSF);
#pragma unroll
    for (int i = 0; i < 8; i++) {
        int c = tid + i * 256;
        float hv = v[i] * scale * w[c];
        ushort_t hi = f2h(hv);
        hh[t * H_DIM + c] = hi;
        hl[t * H_DIM + c] = f2h(hv - h2f_(hi));
    }
}

// ---------------- residual add + RMSNorm (f32 in) -> res f32, h f32, h f16 ----------------
__global__ __launch_bounds__(256) void add_rms2(const float* __restrict__ a,
                                                const float* __restrict__ b,
                                                const float* __restrict__ w,
                                                float* __restrict__ res,
                                                float* __restrict__ hf,
                                                ushort_t* __restrict__ hh) {
    int t = blockIdx.x, tid = threadIdx.x;
    float v[8];
    float ss = 0.f;
#pragma unroll
    for (int i = 0; i < 8; i++) {
        int idx = t * H_DIM + tid + i * 256;
        v[i] = a[idx] + b[idx];
        res[idx] = v[i];
        ss += v[i] * v[i];
    }
#pragma unroll
    for (int o = 32; o; o >>= 1) ss += __shfl_down(ss, o);
    __shared__ float red[4];
    if ((tid & 63) == 0) red[tid >> 6] = ss;
    __syncthreads();
    float tot = red[0] + red[1] + red[2] + red[3];
    float scale = rsqrtf(tot / (float)H_DIM + EPSF);
#pragma unroll
    for (int i = 0; i < 8; i++) {
        int c = tid + i * 256;
        float hv = v[i] * scale * w[c];
        hf[t * H_DIM + c] = hv;
        hh[t * H_DIM + c] = f2h(hv);
    }
}

// ---------------- cast+transpose f32 [R][C(ld)] -> f16 hi/lo [C][R] ----------------
__global__ __launch_bounds__(256) void castT_hl(const float* __restrict__ in,
                                                ushort_t* __restrict__ oh,
                                                ushort_t* __restrict__ ol,
                                                int R, int ld) {
    __shared__ float tile[32][33];
    int r0 = blockIdx.y * 32, c0 = blockIdx.x * 32;
    int tx = threadIdx.x & 31, ty = threadIdx.x >> 5;
#pragma unroll
    for (int i = 0; i < 4; i++)
        tile[ty + 8 * i][tx] = in[(size_t)(r0 + ty + 8 * i) * ld + c0 + tx];
    __syncthreads();
#pragma unroll
    for (int i = 0; i < 4; i++) {
        float v = tile[tx][ty + 8 * i];
        ushort_t hi = f2h(v);
        size_t idx = (size_t)(c0 + ty + 8 * i) * R + r0 + tx;
        oh[idx] = hi;
        ol[idx] = f2h(v - h2f_(hi));
    }
}

// ---------------- cast+transpose f32 [R][C(ld)] -> f16 [C][R], z-batched ----------------
__global__ __launch_bounds__(256) void castT_h(const float* __restrict__ in,
                                               ushort_t* __restrict__ out,
                                               int R, int ld, size_t zstride) {
    in += (size_t)blockIdx.z * zstride;
    out += (size_t)blockIdx.z * zstride;
    __shared__ float tile[32][33];
    int r0 = blockIdx.y * 32, c0 = blockIdx.x * 32;
    int tx = threadIdx.x & 31, ty = threadIdx.x >> 5;
#pragma unroll
    for (int i = 0; i < 4; i++)
        tile[ty + 8 * i][tx] = in[(size_t)(r0 + ty + 8 * i) * ld + c0 + tx];
    __syncthreads();
#pragma unroll
    for (int i = 0; i < 4; i++)
        out[(size_t)(c0 + ty + 8 * i) * R + r0 + tx] = f2h(tile[tx][ty + 8 * i]);
}

// ------- split-f16 MFMA GEMM with split-K: C += (Ah+Al)[M,K] @ (Bh+Bl)[N,K]^T -------
// gridDim.z = KSPLIT; each z-block handles K/KSPLIT; results accumulated via f32 atomics.
// C must be zeroed before launch.
__global__ __launch_bounds__(256) void gemm_f16x3(const ushort_t* __restrict__ Ah,
                                                  const ushort_t* __restrict__ Al_,
                                                  const ushort_t* __restrict__ Bh,
                                                  const ushort_t* __restrict__ Bl_,
                                                  float* __restrict__ C,
                                                  int ldc, int K) {
    __shared__ ushort_t sAh[4096], sAl[4096], sBh[4096], sBl[4096];
    int tid = threadIdx.x, lane = tid & 63, wv = tid >> 6;
    int m0 = blockIdx.y * 128, n0 = blockIdx.x * 128;
    int Kc = K / gridDim.z;
    int kz = blockIdx.z * Kc;
    int wm = (wv & 1) * 64, wn = (wv >> 1) * 64;
    int fr = lane & 15, fq = lane >> 4;
    f32x4 acc[4][4];
#pragma unroll
    for (int i = 0; i < 4; i++)
#pragma unroll
        for (int j = 0; j < 4; j++) acc[i][j] = {0.f, 0.f, 0.f, 0.f};

    size_t aoff = (size_t)(m0 + wv * 32 + (lane >> 2)) * K + (lane & 3) * 8 + kz;
    size_t boff = (size_t)(n0 + wv * 32 + (lane >> 2)) * K + (lane & 3) * 8 + kz;
    const ushort_t* gAh = Ah + aoff;
    const ushort_t* gAl = Al_ + aoff;
    const ushort_t* gBh = Bh + boff;
    const ushort_t* gBl = Bl_ + boff;

    for (int k0 = 0; k0 < Kc; k0 += 32) {
        gld16(gAh, &sAh[(wv * 32) * 32]);
        gld16(gAh + (size_t)16 * K, &sAh[(wv * 32 + 16) * 32]);
        gld16(gAl, &sAl[(wv * 32) * 32]);
        gld16(gAl + (size_t)16 * K, &sAl[(wv * 32 + 16) * 32]);
        gld16(gBh, &sBh[(wv * 32) * 32]);
        gld16(gBh + (size_t)16 * K, &sBh[(wv * 32 + 16) * 32]);
        gld16(gBl, &sBl[(wv * 32) * 32]);
        gld16(gBl + (size_t)16 * K, &sBl[(wv * 32 + 16) * 32]);
        gAh += 32; gAl += 32; gBh += 32; gBl += 32;
        __syncthreads();
        half8 ah[4], al[4], bh[4], bl[4];
#pragma unroll
        for (int i = 0; i < 4; i++) {
            int off = (wm + i * 16 + fr) * 32 + fq * 8;
            ah[i] = *(const half8*)&sAh[off];
            al[i] = *(const half8*)&sAl[off];
        }
#pragma unroll
        for (int j = 0; j < 4; j++) {
            int off = (wn + j * 16 + fr) * 32 + fq * 8;
            bh[j] = *(const half8*)&sBh[off];
            bl[j] = *(const half8*)&sBl[off];
        }
#pragma unroll
        for (int i = 0; i < 4; i++)
#pragma unroll
            for (int j = 0; j < 4; j++) {
                acc[i][j] = __builtin_amdgcn_mfma_f32_16x16x32_f16(ah[i], bh[j], acc[i][j], 0, 0, 0);
                acc[i][j] = __builtin_amdgcn_mfma_f32_16x16x32_f16(ah[i], bl[j], acc[i][j], 0, 0, 0);
                acc[i][j] = __builtin_amdgcn_mfma_f32_16x16x32_f16(al[i], bh[j], acc[i][j], 0, 0, 0);
            }
        __syncthreads();
    }
#pragma unroll
    for (int i = 0; i < 4; i++)
#pragma unroll
        for (int j = 0; j < 4; j++)
#pragma unroll
            for (int r = 0; r < 4; r++) {
                int row = m0 + wm + i * 16 + fq * 4 + r;
                int col = n0 + wn + j * 16 + fr;
                atomicAdd(&C[(size_t)row * ldc + col], acc[i][j][r]);
            }
}

// ---------------- grouped f16 MFMA GEMM (MoE): gathered A rows, scattered C rows ----------------
__global__ __launch_bounds__(256) void moe_gemm(const ushort_t* __restrict__ Ab,
                                                const ushort_t* __restrict__ BtAll,
                                                const int* __restrict__ cnt,
                                                const int* __restrict__ ridx_g,
                                                const int* __restrict__ oidx_g,
                                                ushort_t* __restrict__ Cout,
                                                int N, int K, int ebase) {
    int e = ebase + blockIdx.z;
    int nt = cnt[e];
    int mt0 = blockIdx.y * 128;
    if (mt0 >= nt) return;
    const ushort_t* Bt = BtAll + (size_t)blockIdx.z * N * K;
    int n0 = blockIdx.x * 128;
    __shared__ ushort_t Al[4096];
    __shared__ ushort_t Bl[4096];
    __shared__ int ridx[128], oidx[128];
    int tid = threadIdx.x, lane = tid & 63, wv = tid >> 6;
    if (tid < 128) {
        int ii = mt0 + tid;
        bool v = ii < nt;
        ridx[tid] = v ? ridx_g[e * T_TOK + ii] : -1;
        oidx[tid] = v ? oidx_g[e * T_TOK + ii] : -1;
    }
    __syncthreads();
    int wm = (wv & 1) * 64, wn = (wv >> 1) * 64;
    int fr = lane & 15, fq = lane >> 4;
    f32x4 acc[4][4];
#pragma unroll
    for (int i = 0; i < 4; i++)
#pragma unroll
        for (int j = 0; j < 4; j++) acc[i][j] = {0.f, 0.f, 0.f, 0.f};

    int arow = tid >> 1, akoff = (tid & 1) * 16;
    int ra = ridx[arow];
    const ushort_t* asrc = (ra >= 0) ? (Ab + (size_t)ra * K + akoff) : (const ushort_t*)0;
    const ushort_t* gB = Bt + (size_t)(n0 + wv * 32 + (lane >> 2)) * K + (lane & 3) * 8;

    for (int k0 = 0; k0 < K; k0 += 32) {
        uint4 v0 = {0, 0, 0, 0}, v1 = {0, 0, 0, 0};
        if (ra >= 0) {
            v0 = *(const uint4*)(asrc);
            v1 = *(const uint4*)(asrc + 8);
            asrc += 32;
        }
        gld16(gB, &Bl[(wv * 32) * 32]);
        gld16(gB + (size_t)16 * K, &Bl[(wv * 32 + 16) * 32]);
        gB += 32;
        *(uint4*)&Al[arow * 32 + akoff] = v0;
        *(uint4*)&Al[arow * 32 + akoff + 8] = v1;
        __syncthreads();
        half8 af[4], bfr[4];
#pragma unroll
        for (int i = 0; i < 4; i++) af[i] = *(const half8*)&Al[(wm + i * 16 + fr) * 32 + fq * 8];
#pragma unroll
        for (int j = 0; j < 4; j++) bfr[j] = *(const half8*)&Bl[(wn + j * 16 + fr) * 32 + fq * 8];
#pragma unroll
        for (int i = 0; i < 4; i++)
#pragma unroll
            for (int j = 0; j < 4; j++)
                acc[i][j] = __builtin_amdgcn_mfma_f32_16x16x32_f16(af[i], bfr[j], acc[i][j], 0, 0, 0);
        __syncthreads();
    }
#pragma unroll
    for (int i = 0; i < 4; i++)
#pragma unroll
        for (int j = 0; j < 4; j++)
#pragma unroll
            for (int r = 0; r < 4; r++) {
                int lr = wm + i * 16 + fq * 4 + r;
                if (mt0 + lr < nt) {
                    int orow = oidx[lr];
                    Cout[(size_t)orow * N + n0 + wn + j * 16 + fr] = f2h(acc[i][j][r]);
                }
            }
}

// ---------------- QK RMSNorm + neox RoPE (in-place on f32 qkv) ----------------
__global__ __launch_bounds__(128) void qk_rope(float* __restrict__ qkv,
                                               const float* __restrict__ qw,
                                               const float* __restrict__ kw,
                                               const int* __restrict__ positions) {
    int t = blockIdx.x / (NH + NKV);
    int hh = blockIdx.x % (NH + NKV);
    float* x;
    const float* w;
    if (hh < NH) { x = qkv + (size_t)t * 3072 + hh * HD; w = qw; }
    else         { x = qkv + (size_t)t * 3072 + 2048 + (hh - NH) * HD; w = kw; }
    int tid = threadIdx.x;
    float v = x[tid];
    float ss = v * v;
#pragma unroll
    for (int o = 32; o; o >>= 1) ss += __shfl_down(ss, o);
    __shared__ float red[2];
    if ((tid & 63) == 0) red[tid >> 6] = ss;
    __syncthreads();
    float tot = red[0] + red[1];
    float scale = rsqrtf(tot / (float)HD + EPSF);
    float xn = v * scale * w[tid];
    __shared__ float buf[HD];
    buf[tid] = xn;
    __syncthreads();
    if (tid < 64) {
        float x1 = buf[tid], x2 = buf[tid + 64];
        float invf = expf(-((float)tid / 64.0f) * logf(1000000.0f));
        float ang = (float)positions[t] * invf;
        float c = cosf(ang), s = sinf(ang);
        x[tid] = x1 * c - x2 * s;
        x[tid + 64] = x2 * c + x1 * s;
    }
}

// ---------------- MFMA flash attention: f16 hi/lo split (3-MFMA), f32 softmax ----------------
// block = 256 threads (4 waves), one block per (head, 64-query tile).
// wave w owns q-rows [w*16, w*16+16). S tile 64x64 per k-step via 16x16x32 f16 MFMA.
#define ATT_SCALE 0.08838834764831845f
__global__ __launch_bounds__(256) void attn_mfma(const float* __restrict__ qkv,
                                                 ushort_t* __restrict__ ohp,
                                                 ushort_t* __restrict__ olp) {
    // padded strides: 136 halves (K rows), 72 halves (Vt/P rows) -> 2-way max bank aliasing
    __shared__ _Float16 sKh[64 * 136], sKl[64 * 136];
    __shared__ _Float16 sVh[128 * 72], sVl[128 * 72];
    __shared__ _Float16 sQh[64 * 136], sQl[64 * 136];  // reused as Ph/Pl [64][72] after preload

    int qi = blockIdx.x, h = blockIdx.y;
    int q0 = qi * 64, g = h >> 2;
    int tid = threadIdx.x, lane = tid & 63, wv = tid >> 6;
    int quad = lane >> 4, n16 = lane & 15;

    // ---- stage Q tile (hi/lo f16), row-major padded ----
    {
        int r = tid >> 2, c0 = (tid & 3) * 32;
        const float* qp = qkv + (size_t)(q0 + r) * 3072 + h * HD + c0;
#pragma unroll
        for (int i = 0; i < 8; i++) {
            float4 v = *(const float4*)(qp + i * 4);
            float vv[4] = {v.x, v.y, v.z, v.w};
            us4 h4, l4;
#pragma unroll
            for (int p = 0; p < 4; p++) {
                _Float16 hi = (_Float16)vv[p];
                h4[p] = __builtin_bit_cast(ushort_t, hi);
                l4[p] = __builtin_bit_cast(ushort_t, (_Float16)(vv[p] - (float)hi));
            }
            *(us4*)&sQh[r * 136 + c0 + i * 4] = h4;
            *(us4*)&sQl[r * 136 + c0 + i * 4] = l4;
        }
    }
    __syncthreads();
    // ---- preload Q A-frags: A[m=lane&15][k=quad*8+j], k-step 32 ----
    half8 qh[4], ql[4];
#pragma unroll
    for (int ks = 0; ks < 4; ks++) {
        int off = (wv * 16 + n16) * 136 + ks * 32 + quad * 8;
        qh[ks] = *(const half8*)&sQh[off];
        ql[ks] = *(const half8*)&sQl[off];
    }
    _Float16* sPh = sQh;  // [64][72]
    _Float16* sPl = sQl;

    float m_r[4], l_r[4];
#pragma unroll
    for (int r = 0; r < 4; r++) { m_r[r] = -1e30f; l_r[r] = 0.f; }
    f32x4 acc[8];
#pragma unroll
    for (int d = 0; d < 8; d++) acc[d] = {0.f, 0.f, 0.f, 0.f};

    for (int kt = 0; kt <= qi; kt++) {
        __syncthreads();  // previous tile fully consumed
        // ---- stage K row-major + V transposed (hi/lo f16) ----
        {
            int r = tid >> 2, c0 = (tid & 3) * 32;
            const float* kp = qkv + (size_t)(kt * 64 + r) * 3072 + 2048 + g * HD + c0;
#pragma unroll
            for (int i = 0; i < 8; i++) {
                float4 v = *(const float4*)(kp + i * 4);
                float vv[4] = {v.x, v.y, v.z, v.w};
                us4 h4, l4;
#pragma unroll
                for (int p = 0; p < 4; p++) {
                    _Float16 hi = (_Float16)vv[p];
                    h4[p] = __builtin_bit_cast(ushort_t, hi);
                    l4[p] = __builtin_bit_cast(ushort_t, (_Float16)(vv[p] - (float)hi));
                }
                *(us4*)&sKh[r * 136 + c0 + i * 4] = h4;
                *(us4*)&sKl[r * 136 + c0 + i * 4] = l4;
            }
            int cv0 = (tid & 3) * 4;
            const float* vp = qkv + (size_t)(kt * 64 + r) * 3072 + 2560 + g * HD + cv0;
#pragma unroll
            for (int i = 0; i < 8; i++) {
                float4 v = *(const float4*)(vp + i * 16);
                float vv[4] = {v.x, v.y, v.z, v.w};
#pragma unroll
                for (int p = 0; p < 4; p++) {
                    int d = cv0 + i * 16 + p;
                    _Float16 hi = (_Float16)vv[p];
                    sVh[d * 72 + r] = hi;
                    sVl[d * 72 + r] = (_Float16)(vv[p] - (float)hi);
                }
            }
        }
        __syncthreads();

        // ---- S = Q K^T : per wave 16q x 64k, hi*hi + hi*lo + lo*hi ----
        f32x4 s[4];
#pragma unroll
        for (int jt = 0; jt < 4; jt++) s[jt] = {0.f, 0.f, 0.f, 0.f};
#pragma unroll
        for (int ks = 0; ks < 4; ks++)
#pragma unroll
            for (int jt = 0; jt < 4; jt++) {
                int off = (jt * 16 + n16) * 136 + ks * 32 + quad * 8;
                half8 bh = *(const half8*)&sKh[off];
                half8 bl = *(const half8*)&sKl[off];
                s[jt] = __builtin_amdgcn_mfma_f32_16x16x32_f16(qh[ks], bh, s[jt], 0, 0, 0);
                s[jt] = __builtin_amdgcn_mfma_f32_16x16x32_f16(qh[ks], bl, s[jt], 0, 0, 0);
                s[jt] = __builtin_amdgcn_mfma_f32_16x16x32_f16(ql[ks], bh, s[jt], 0, 0, 0);
            }

        // ---- online softmax in C-layout (row = quad*4+r, col = jt*16+n16) ----
        bool last = (kt == qi);
        int lrow_base = wv * 16 + quad * 4;
#pragma unroll
        for (int r = 0; r < 4; r++) {
            float rm = -1e30f;
#pragma unroll
            for (int jt = 0; jt < 4; jt++) {
                float sv = s[jt][r] * ATT_SCALE;
                if (last && (jt * 16 + n16 > lrow_base + r)) sv = -1e30f;
                s[jt][r] = sv;
                rm = fmaxf(rm, sv);
            }
            rm = fmaxf(rm, __shfl_xor(rm, 1));
            rm = fmaxf(rm, __shfl_xor(rm, 2));
            rm = fmaxf(rm, __shfl_xor(rm, 4));
            rm = fmaxf(rm, __shfl_xor(rm, 8));
            float mo = m_r[r], mn = fmaxf(mo, rm);
            float al = __expf(mo - mn);
            float ls = 0.f;
#pragma unroll
            for (int jt = 0; jt < 4; jt++) {
                float p = __expf(s[jt][r] - mn);
                ls += p;
                _Float16 phi = (_Float16)p;
                int poff = (lrow_base + r) * 72 + jt * 16 + n16;
                sPh[poff] = phi;
                sPl[poff] = (_Float16)(p - (float)phi);
            }
            ls += __shfl_xor(ls, 1);
            ls += __shfl_xor(ls, 2);
            ls += __shfl_xor(ls, 4);
            ls += __shfl_xor(ls, 8);
            l_r[r] = l_r[r] * al + ls;
            m_r[r] = mn;
#pragma unroll
            for (int dt = 0; dt < 8; dt++) acc[dt][r] *= al;
        }
        __syncthreads();  // P visible (also orders same-wave LDS write->read)

        // ---- PV: P (A-layout via LDS round-trip) x V (B from transposed Vt) ----
        half8 pah[2], pal[2];
#pragma unroll
        for (int ks = 0; ks < 2; ks++) {
            int off = (wv * 16 + n16) * 72 + ks * 32 + quad * 8;
            pah[ks] = *(const half8*)&sPh[off];
            pal[ks] = *(const half8*)&sPl[off];
        }
#pragma unroll
        for (int dt = 0; dt < 8; dt++)
#pragma unroll
            for (int ks = 0; ks < 2; ks++) {
                int off = (dt * 16 + n16) * 72 + ks * 32 + quad * 8;
                half8 vh = *(const half8*)&sVh[off];
                half8 vl = *(const half8*)&sVl[off];
                acc[dt] = __builtin_amdgcn_mfma_f32_16x16x32_f16(pah[ks], vh, acc[dt], 0, 0, 0);
                acc[dt] = __builtin_amdgcn_mfma_f32_16x16x32_f16(pah[ks], vl, acc[dt], 0, 0, 0);
                acc[dt] = __builtin_amdgcn_mfma_f32_16x16x32_f16(pal[ks], vh, acc[dt], 0, 0, 0);
            }
    }

    // ---- epilogue: o = acc / l, written as f16 hi/lo planes ----
#pragma unroll
    for (int r = 0; r < 4; r++) {
        float inv = 1.f / l_r[r];
        int row = q0 + wv * 16 + quad * 4 + r;
#pragma unroll
        for (int dt = 0; dt < 8; dt++) {
            float val = acc[dt][r] * inv;
            _Float16 hi = (_Float16)val;
            size_t idx = (size_t)row * 2048 + h * HD + dt * 16 + n16;
            ohp[idx] = __builtin_bit_cast(ushort_t, hi);
            olp[idx] = __builtin_bit_cast(ushort_t, (_Float16)(val - (float)hi));
        }
    }
}

// ---------------- router: softmax over 8 experts, top-2, bucket by expert ----------------
__global__ __launch_bounds__(256) void router(const float* __restrict__ h2,
                                              const float* __restrict__ gate_w,
                                              int* __restrict__ cnt,
                                              int* __restrict__ btok,
                                              int* __restrict__ bslot,
                                              float* __restrict__ wslot) {
    int t = blockIdx.x, tid = threadIdx.x;
    int e = tid & 7, c = tid >> 3;
    float part = 0.f;
    for (int i = 0; i < 64; i++) {
        int hh = c * 64 + i;
        part += h2[(size_t)t * H_DIM + hh] * gate_w[hh * NEXP + e];
    }
    __shared__ float red[256];
    red[tid] = part;
    __syncthreads();
    for (int s = 128; s >= 8; s >>= 1) {
        if (tid < s) red[tid] += red[tid + s];
        __syncthreads();
    }
    if (tid == 0) {
        float mx = -1e30f;
        for (int i = 0; i < NEXP; i++) mx = fmaxf(mx, red[i]);
        float p[NEXP];
        for (int i = 0; i < NEXP; i++) p[i] = expf(red[i] - mx);
        int i1 = 0;
        for (int i = 1; i < NEXP; i++) if (p[i] > p[i1]) i1 = i;
        int i2 = (i1 == 0) ? 1 : 0;
        for (int i = 0; i < NEXP; i++) if (i != i1 && p[i] > p[i2]) i2 = i;
        float denom = p[i1] + p[i2];
        wslot[2 * t] = p[i1] / denom;
        wslot[2 * t + 1] = p[i2] / denom;
        int pos = atomicAdd(&cnt[i1], 1);
        btok[i1 * T_TOK + pos] = t; bslot[i1 * T_TOK + pos] = 2 * t;
        pos = atomicAdd(&cnt[i2], 1);
        btok[i2 * T_TOK + pos] = t; bslot[i2 * T_TOK + pos] = 2 * t + 1;
    }
}

// ---------------- SwiGLU: gu f16 [2048][1536] -> act f16 [2048][768] ----------------
__global__ __launch_bounds__(256) void swiglu(const ushort_t* __restrict__ gu,
                                              ushort_t* __restrict__ act) {
    int idx = blockIdx.x * 256 + threadIdx.x;
    int s = idx / I_DIM, i = idx - s * I_DIM;
    float g = h2f_(gu[(size_t)s * (2 * I_DIM) + i]);
    float u = h2f_(gu[(size_t)s * (2 * I_DIM) + I_DIM + i]);
    act[idx] = f2h(g / (1.f + expf(-g)) * u);
}

// ---------------- combine: out[t] = w0*dbuf[2t] + w1*dbuf[2t+1] ----------------
__global__ __launch_bounds__(256) void combine(const ushort_t* __restrict__ dbuf,
                                               const float* __restrict__ wslot,
                                               float* __restrict__ out) {
    int idx = blockIdx.x * 256 + threadIdx.x;
    int t = idx >> 11;
    out[idx] = wslot[2 * t] * h2f_(dbuf[(size_t)(2 * t) * H_DIM + (idx & 2047)]) +
               wslot[2 * t + 1] * h2f_(dbuf[(size_t)(2 * t + 1) * H_DIM + (idx & 2047)]);
}

extern "C" void kernel_launch(void* const* d_in, const int* in_sizes, int n_in,
                              void* d_out, int out_size, void* d_ws, size_t ws_size,
                              hipStream_t stream) {
    const int* positions = (const int*)d_in[0];
    const float* hs = (const float*)d_in[1];
    const float* resid = (const float*)d_in[2];
    const float* w_qkv = (const float*)d_in[3];
    const float* w_o = (const float*)d_in[4];
    const float* q_norm_w = (const float*)d_in[5];
    const float* k_norm_w = (const float*)d_in[6];
    const float* ln1_w = (const float*)d_in[7];
    const float* ln2_w = (const float*)d_in[8];
    const float* gate_w = (const float*)d_in[9];
    const float* w_gu = (const float*)d_in[10];
    const float* w_dn = (const float*)d_in[11];

    float* out = (float*)d_out;
    float* res2 = out + (size_t)T_TOK * H_DIM;

    const size_t MB = 1ull << 20;
    char* W = (char*)d_ws;
    // region A: 0-8 MiB
    float*    res1   = (float*)(W + 0);          // live steps 2-8
    ushort_t* gub    = (ushort_t*)(W + 0);       // f16 [2048][1536] 6 MiB, live 10-11
    ushort_t* dbuf   = (ushort_t*)(W + 0);       // f16 [2048][2048] 8 MiB, live 12-13
    // region B: 8-16 MiB
    ushort_t* h1h    = (ushort_t*)(W + 8 * MB);  // live 2-3
    ushort_t* h1l    = (ushort_t*)(W + 12 * MB);
    ushort_t* ohp    = (ushort_t*)(W + 8 * MB);  // live 6-7
    ushort_t* olp    = (ushort_t*)(W + 12 * MB);
    ushort_t* h2h    = (ushort_t*)(W + 8 * MB);  // live 8-10
    ushort_t* actb   = (ushort_t*)(W + 12 * MB); // 3 MiB, live 11-12
    // region C: 16-28 MiB (and 16-41.2 during MoE)
    float*    qkvf   = (float*)(W + 16 * MB);    // 12 MiB, live 3-6
    float*    oprojf = (float*)(W + 16 * MB);    // 8 MiB, live 7-8
    ushort_t* wTmoe  = (ushort_t*)(W + 16 * MB); // up to 25.2 MiB (4x gate_up / 8x down), live 10-12
    // region D: 28-44 MiB (qkv / w_o weight transposes, live steps 3-7 only)
    ushort_t* wTh    = (ushort_t*)(W + 28 * MB); // qkv chunk hi 6 MiB / w_o hi 8 MiB
    ushort_t* wTl_q  = (ushort_t*)(W + 34 * MB); // qkv chunk lo 6 MiB
    ushort_t* wTl_o  = (ushort_t*)(W + 36 * MB); // w_o lo 8 MiB (28-36 hi, 36-44 lo)
    // region E: 40-48 MiB
    float*    h2f    = (float*)(W + 40 * MB);    // 8 MiB, live 8-9
    // buckets: 48 MiB+
    int*      cnt    = (int*)(W + 48 * MB);
    int*      btok   = cnt + 16;
    int*      bslot  = btok + NEXP * T_TOK;
    float*    wslot  = (float*)(bslot + NEXP * T_TOK);

    // 1+2. res1 = hs + resid; h1 = rms(res1)*ln1 as f16 hi/lo
    add_rms1<<<T_TOK, 256, 0, stream>>>(hs, resid, ln1_w, res1, h1h, h1l);
    // 3. qkv = h1 @ w_qkv in two N-chunks of 1536, split-K=4 (384 blocks/launch, atomic f32)
    hipMemsetAsync(qkvf, 0, (size_t)T_TOK * 3072 * 4, stream);
    for (int c = 0; c < 2; c++) {
        castT_hl<<<dim3(1536 / 32, 2048 / 32), 256, 0, stream>>>(
            w_qkv + c * 1536, wTh, wTl_q, 2048, 3072);
        gemm_f16x3<<<dim3(1536 / 128, 1024 / 128, 4), 256, 0, stream>>>(
            h1h, h1l, wTh, wTl_q, qkvf + c * 1536, 3072, 2048);
    }
    // 4. q/k RMSNorm + RoPE in place (f32)
    qk_rope<<<T_TOK * (NH + NKV), 128, 0, stream>>>(qkvf, q_norm_w, k_norm_w, positions);
    // 5. w_o transpose hi/lo
    castT_hl<<<dim3(2048 / 32, 2048 / 32), 256, 0, stream>>>(w_o, wTh, wTl_o, 2048, 2048);
    // 6. MFMA flash attention -> o hi/lo f16 planes
    attn_mfma<<<dim3(T_TOK / 64, NH), 256, 0, stream>>>(qkvf, ohp, olp);
    // 7. oproj = attn_out @ w_o, split-K=2 (256 blocks, atomic f32)
    hipMemsetAsync(oprojf, 0, (size_t)T_TOK * H_DIM * 4, stream);
    gemm_f16x3<<<dim3(2048 / 128, 1024 / 128, 2), 256, 0, stream>>>(
        ohp, olp, wTh, wTl_o, oprojf, 2048, 2048);
    // 8. res2 = oproj + res1 (-> d_out); h2 f32 + f16
    add_rms2<<<T_TOK, 256, 0, stream>>>(oprojf, res1, ln2_w, res2, h2f, h2h);
    // 9. router (f32 logits)
    hipMemsetAsync(cnt, 0, NEXP * sizeof(int), stream);
    router<<<T_TOK, 256, 0, stream>>>(h2f, gate_w, cnt, btok, bslot, wslot);
    // 10. MoE gate_up in 2 chunks of 4 experts (weights 25.2 MiB at W+16MB; gub at W+0)
    for (int c = 0; c < 2; c++) {
        castT_h<<<dim3(1536 / 32, 2048 / 32, 4), 256, 0, stream>>>(
            w_gu + (size_t)c * 4 * 2048 * 1536, wTmoe, 2048, 1536, (size_t)2048 * 1536);
        moe_gemm<<<dim3(1536 / 128, 8, 4), 256, 0, stream>>>(
            h2h, wTmoe, cnt, btok, bslot, gub, 1536, 2048, c * 4);
    }
    // 11. SwiGLU
    swiglu<<<(2048 * I_DIM) / 256, 256, 0, stream>>>(gub, actb);
    // 12. MoE down, all 8 experts in one round
    castT_h<<<dim3(2048 / 32, 768 / 32, 8), 256, 0, stream>>>(
        w_dn, wTmoe, 768, 2048, (size_t)768 * 2048);
    moe_gemm<<<dim3(2048 / 128, 8, 8), 256, 0, stream>>>(
        actb, wTmoe, cnt, bslot, bslot, dbuf, 2048, 768, 0);
    // 13. weighted combine
    combine<<<(T_TOK * H_DIM) / 256, 256, 0, stream>>>(dbuf, wslot, out);
}